// Round 5
// baseline (411.918 us; speedup 1.0000x reference)
//
#include <hip/hip_runtime.h>
#include <hip/hip_bf16.h>

// Problem constants: B=2048, D=3, K=64, H=768, N=4096
#define BATCH   2048
#define DEPTH   3
#define FANOUT  64
#define HID     768
#define NNODES  4096
#define NPAIRS  (BATCH * DEPTH)   // 6144
#define CAP     16                // per-node capacity before overflow
#define NTAIL   64                // overflow tail blocks (dormant in practice)
#define SCHUNK  4                 // samples per W pass

// ---- ws layout (ints) ----
#define WS_COUNT 0
#define WS_OCNT  NNODES                     // 4096 (1 int, padded to 4)
#define WS_LIST  (NNODES + 4)               // 4100
#define WS_OVFL  (WS_LIST + NNODES * CAP)
#define WS_ZERO_INTS (NNODES + 4)

__global__ __launch_bounds__(256) void bin_kernel(const int* __restrict__ nodes,
                                                  int* __restrict__ ws) {
    int idx = blockIdx.x * 256 + threadIdx.x;
    if (idx >= NPAIRS) return;
    int n = nodes[idx];
    int pos = atomicAdd(&ws[WS_COUNT + n], 1);
    if (pos < CAP) {
        ws[WS_LIST + n * CAP + pos] = idx;
    } else {
        int op = atomicAdd(&ws[WS_OCNT], 1);
        ws[WS_OVFL + op] = idx;
    }
}

// Compute 2 passes x 4 rows for SC samples. Lane layout: rg=lane>>4 selects
// row within pass, sub=lane&15 covers H (12 float4/lane). 4-step 16-lane
// shuffle reduce (masks 1,2,4,8). Static SC -> no runtime-indexed arrays.
template <int SC>
__device__ __forceinline__ void compute_passes(
    const float4* __restrict__ w4,      // W + (n*FANOUT + kh*32)*HID, as float4
    const float (*s_pool)[HID],
    float (*s_log)[32],
    const float* s_bias,                // [32] local
    int wave, int lane)
{
    const int sub = lane & 15;
    const int rg  = lane >> 4;
#pragma unroll 1
    for (int pass = 0; pass < 2; ++pass) {
        const int kl = wave * 8 + pass * 4 + rg;    // 0..31 local row
        const float4* wr = w4 + (size_t)kl * (HID / 4);
        float acc[SC];
#pragma unroll
        for (int s = 0; s < SC; ++s) acc[s] = 0.f;
#pragma unroll
        for (int it = 0; it < 12; ++it) {
            float4 w = wr[sub + 16 * it];
#pragma unroll
            for (int s = 0; s < SC; ++s) {
                float4 a = reinterpret_cast<const float4*>(&s_pool[s][0])[sub + 16 * it];
                acc[s] += w.x * a.x + w.y * a.y + w.z * a.z + w.w * a.w;
            }
        }
#pragma unroll
        for (int s = 0; s < SC; ++s) {
            float v = acc[s];
            v += __shfl_xor(v, 1, 64);
            v += __shfl_xor(v, 2, 64);
            v += __shfl_xor(v, 4, 64);
            v += __shfl_xor(v, 8, 64);
            if (sub == 0) s_log[s][kl] = v + s_bias[kl];
        }
    }
}

// Grid: [0, NNODES)            -> node n, k-half 0 (rows 0..31)
//       [NNODES, 2*NNODES)     -> node n, k-half 1 (rows 32..63)
//       [2*NNODES, +NTAIL)     -> overflow sweep (normally empty)
__global__ __launch_bounds__(256, 6) void node_gemm_kernel(
    const float* __restrict__ pooled,   // [B, H]
    const float* __restrict__ W,        // [N, K, H]
    const float* __restrict__ bias,     // [N, K]
    const int*   __restrict__ nodes,    // [B, D]
    int*         __restrict__ ws,
    float*       __restrict__ logits)   // [B, D, K]
{
    __shared__ int   s_pairs[CAP];
    __shared__ float s_bias[32];
    __shared__ float s_pool[SCHUNK][HID];
    __shared__ float s_log[SCHUNK][32];

    const int tid  = threadIdx.x;
    const int wave = tid >> 6;
    const int lane = tid & 63;

    int n, kh, c;
    int ovfl_stride = 0, ovfl_i = 0, oc = 0;

    if (blockIdx.x < 2 * NNODES) {
        n  = blockIdx.x & (NNODES - 1);
        kh = blockIdx.x >> 12;
        c  = ws[WS_COUNT + n];
        if (c == 0) return;
        c = min(c, CAP);
        if (tid < c) s_pairs[tid] = ws[WS_LIST + (size_t)n * CAP + tid];
    } else {
        const int t = (int)blockIdx.x - 2 * NNODES;   // [0, NTAIL)
        oc = min(ws[WS_OCNT], NPAIRS);
        kh = t & 1;
        ovfl_i = t >> 1;
        ovfl_stride = NTAIL >> 1;
        if (ovfl_i >= oc) return;
        c = -1;  // flag: overflow mode
    }

    if (c > 0) {
        // ---- normal node path ----
        if (tid < 32) s_bias[tid] = bias[(size_t)n * FANOUT + kh * 32 + tid];
        __syncthreads();
        const float4* w4 = reinterpret_cast<const float4*>(
            W + ((size_t)n * FANOUT + kh * 32) * HID);

        for (int base = 0; base < c; base += SCHUNK) {
            const int sc = min(c - base, SCHUNK);
            const int* pair_chunk = s_pairs + base;

            for (int idx = tid; idx < sc * (HID / 4); idx += 256) {
                int s = idx / (HID / 4), f = idx % (HID / 4);
                int b = pair_chunk[s] / DEPTH;
                reinterpret_cast<float4*>(&s_pool[s][0])[f] =
                    reinterpret_cast<const float4*>(pooled + (size_t)b * HID)[f];
            }
            __syncthreads();

            switch (sc) {
            case 1: compute_passes<1>(w4, s_pool, s_log, s_bias, wave, lane); break;
            case 2: compute_passes<2>(w4, s_pool, s_log, s_bias, wave, lane); break;
            case 3: compute_passes<3>(w4, s_pool, s_log, s_bias, wave, lane); break;
            default: compute_passes<4>(w4, s_pool, s_log, s_bias, wave, lane); break;
            }
            __syncthreads();

            for (int idx = tid; idx < sc * 32; idx += 256) {
                int s = idx >> 5, kl = idx & 31;
                logits[(size_t)pair_chunk[s] * FANOUT + kh * 32 + kl] = s_log[s][kl];
            }
            __syncthreads();   // protect s_pool/s_log before next chunk
        }
    } else {
        // ---- overflow sweep (c == -1) ----
        for (int i = ovfl_i; i < oc; i += ovfl_stride) {
            if (tid == 0) s_pairs[0] = ws[WS_OVFL + i];
            __syncthreads();
            const int pair = s_pairs[0];
            const int nn = nodes[pair];
            if (tid < 32) s_bias[tid] = bias[(size_t)nn * FANOUT + kh * 32 + tid];
            const int b = pair / DEPTH;
            for (int f = tid; f < HID / 4; f += 256)
                reinterpret_cast<float4*>(&s_pool[0][0])[f] =
                    reinterpret_cast<const float4*>(pooled + (size_t)b * HID)[f];
            __syncthreads();
            const float4* w4 = reinterpret_cast<const float4*>(
                W + ((size_t)nn * FANOUT + kh * 32) * HID);
            compute_passes<1>(w4, s_pool, s_log, s_bias, wave, lane);
            __syncthreads();
            if (tid < 32)
                logits[(size_t)pair * FANOUT + kh * 32 + tid] = s_log[0][tid];
            __syncthreads();
        }
    }
}

// Per-sample CE loss from global logits. One wave per sample, lane = k.
__global__ __launch_bounds__(256) void loss_kernel(
    const float* __restrict__ logits,   // [B, D, K]
    const int*   __restrict__ path,     // [B, D]
    float*       __restrict__ losses)   // [B]
{
    const int wave = threadIdx.x >> 6;
    const int lane = threadIdx.x & 63;
    const int b = blockIdx.x * 4 + wave;
    if (b >= BATCH) return;
    const float* lg = logits + (size_t)b * DEPTH * FANOUT;
    float loss = 0.f;
#pragma unroll
    for (int d = 0; d < DEPTH; ++d) {
        float x = lg[d * FANOUT + lane];
        float m = x;
#pragma unroll
        for (int off = 32; off > 0; off >>= 1)
            m = fmaxf(m, __shfl_xor(m, off, 64));
        float e = expf(x - m);
#pragma unroll
        for (int off = 32; off > 0; off >>= 1)
            e += __shfl_xor(e, off, 64);
        float lse = m + logf(e);
        int t = path[b * DEPTH + d];
        loss += lse - __shfl(x, t, 64);
    }
    if (lane == 0) losses[b] = loss;
}

extern "C" void kernel_launch(void* const* d_in, const int* in_sizes, int n_in,
                              void* d_out, int out_size, void* d_ws, size_t ws_size,
                              hipStream_t stream) {
    const float* pooled = (const float*)d_in[0];  // [B, H]
    const int*   nodes  = (const int*)d_in[1];    // [B, D]
    const int*   path   = (const int*)d_in[2];    // [B, D]
    const float* W      = (const float*)d_in[3];  // [N, K, H]
    const float* bias   = (const float*)d_in[4];  // [N, K]

    float* losses = (float*)d_out;                // [B]
    float* logits = (float*)d_out + BATCH;        // [B, D, K]
    int*   ws     = (int*)d_ws;

    hipMemsetAsync(ws, 0, WS_ZERO_INTS * sizeof(int), stream);
    hipLaunchKernelGGL(bin_kernel, dim3((NPAIRS + 255) / 256), dim3(256),
                       0, stream, nodes, ws);
    hipLaunchKernelGGL(node_gemm_kernel, dim3(2 * NNODES + NTAIL), dim3(256),
                       0, stream, pooled, W, bias, nodes, ws, logits);
    hipLaunchKernelGGL(loss_kernel, dim3((BATCH + 3) / 4), dim3(256),
                       0, stream, logits, path, losses);
}

// Round 6
// 134.862 us; speedup vs baseline: 3.0544x; 3.0544x over previous
//
#include <hip/hip_runtime.h>
#include <hip/hip_bf16.h>

// Problem constants: B=2048, D=3, K=64, H=768, N=4096
#define BATCH   2048
#define DEPTH   3
#define FANOUT  64
#define HID     768
#define NNODES  4096
#define NPAIRS  (BATCH * DEPTH)   // 6144
#define CAP     16                // per-node capacity before overflow
#define NTAIL   64                // overflow tail blocks (dormant in practice)
#define SCHUNK  4                 // samples per W pass (c>4 -> extra pass, L2-warm)

// ---- ws layout (ints) ----
#define WS_COUNT 0
#define WS_OCNT  NNODES                     // 4096 (1 int, padded to 4)
#define WS_LIST  (NNODES + 4)               // 4100
#define WS_OVFL  (WS_LIST + NNODES * CAP)
#define WS_ZERO_INTS (NNODES + 4)

__global__ __launch_bounds__(256) void bin_kernel(const int* __restrict__ nodes,
                                                  int* __restrict__ ws) {
    int idx = blockIdx.x * 256 + threadIdx.x;
    if (idx >= NPAIRS) return;
    int n = nodes[idx];
    int pos = atomicAdd(&ws[WS_COUNT + n], 1);
    if (pos < CAP) {
        ws[WS_LIST + n * CAP + pos] = idx;
    } else {
        int op = atomicAdd(&ws[WS_OCNT], 1);
        ws[WS_OVFL + op] = idx;
    }
}

// R4's exact W-stream layout (64 lanes x float4, 3 loads = one contiguous 3KB
// row per wave-iteration), but the sample loop is STATIC (template SC) and the
// 6-step butterflies are interleaved off-major so the SC reduce chains overlap.
template <int SC>
__device__ __forceinline__ void compute_rows(
    const float4* __restrict__ w4,      // W + n*FANOUT*HID as float4
    const float (*s_pool)[HID],
    float (*s_log)[FANOUT],
    const float* s_bias,                // [FANOUT]
    int wave, int lane)
{
#pragma unroll 4
    for (int kk = 0; kk < 16; ++kk) {
        const int k = wave * 16 + kk;
        const float4* wr = w4 + (size_t)k * (HID / 4);
        float4 w0 = wr[lane], w1 = wr[lane + 64], w2 = wr[lane + 128];
        float v[SC];
#pragma unroll
        for (int s = 0; s < SC; ++s) {
            const float4* a4 = reinterpret_cast<const float4*>(&s_pool[s][0]);
            float4 a0 = a4[lane], a1 = a4[lane + 64], a2 = a4[lane + 128];
            v[s] = w0.x * a0.x + w0.y * a0.y + w0.z * a0.z + w0.w * a0.w
                 + w1.x * a1.x + w1.y * a1.y + w1.z * a1.z + w1.w * a1.w
                 + w2.x * a2.x + w2.y * a2.y + w2.z * a2.z + w2.w * a2.w;
        }
        // off-major: SC independent chains advance together (ILP across s)
#pragma unroll
        for (int off = 32; off > 0; off >>= 1) {
#pragma unroll
            for (int s = 0; s < SC; ++s)
                v[s] += __shfl_xor(v[s], off, 64);
        }
        if (lane == 0) {
#pragma unroll
            for (int s = 0; s < SC; ++s)
                s_log[s][k] = v[s] + s_bias[k];
        }
    }
}

// One block per node; tail blocks sweep the (normally empty) overflow list.
__global__ __launch_bounds__(256) void node_gemm_kernel(
    const float* __restrict__ pooled,   // [B, H]
    const float* __restrict__ W,        // [N, K, H]
    const float* __restrict__ bias,     // [N, K]
    const int*   __restrict__ nodes,    // [B, D]
    int*         __restrict__ ws,
    float*       __restrict__ logits)   // [B, D, K]
{
    __shared__ int   s_pairs[CAP];
    __shared__ float s_bias[FANOUT];
    __shared__ float s_pool[SCHUNK][HID];
    __shared__ float s_log[SCHUNK][FANOUT];

    const int tid  = threadIdx.x;
    const int wave = tid >> 6;
    const int lane = tid & 63;

    int c = 0;
    int n = -1;

    if (blockIdx.x < NNODES) {
        n = blockIdx.x;
        c = ws[WS_COUNT + n];
        if (c == 0) return;
        c = min(c, CAP);
        if (tid < c) s_pairs[tid] = ws[WS_LIST + (size_t)n * CAP + tid];
    } else {
        const int oc = min(ws[WS_OCNT], NPAIRS);
        const int i  = (int)blockIdx.x - NNODES;
        if (i >= oc) return;
        c = 1;
        if (tid == 0) s_pairs[0] = ws[WS_OVFL + i];
        __syncthreads();
        n = nodes[s_pairs[0]];
    }
    if (tid < FANOUT) s_bias[tid] = bias[(size_t)n * FANOUT + tid];
    __syncthreads();

    const float4* w4 = reinterpret_cast<const float4*>(W + (size_t)n * FANOUT * HID);

    for (int base = 0; base < c; base += SCHUNK) {
        const int sc = min(c - base, SCHUNK);
        const int* pair_chunk = s_pairs + base;

        // Stage the sc pooled vectors into LDS (coalesced float4)
        for (int idx = tid; idx < sc * (HID / 4); idx += 256) {
            int s = idx / (HID / 4);
            int f = idx % (HID / 4);
            int b = pair_chunk[s] / DEPTH;
            reinterpret_cast<float4*>(&s_pool[s][0])[f] =
                reinterpret_cast<const float4*>(pooled + (size_t)b * HID)[f];
        }
        __syncthreads();

        switch (sc) {
        case 1: compute_rows<1>(w4, s_pool, s_log, s_bias, wave, lane); break;
        case 2: compute_rows<2>(w4, s_pool, s_log, s_bias, wave, lane); break;
        case 3: compute_rows<3>(w4, s_pool, s_log, s_bias, wave, lane); break;
        default: compute_rows<4>(w4, s_pool, s_log, s_bias, wave, lane); break;
        }
        __syncthreads();

        // Coalesced logits writeout
        for (int idx = tid; idx < sc * FANOUT; idx += 256) {
            int s = idx >> 6, k = idx & 63;
            logits[(size_t)pair_chunk[s] * FANOUT + k] = s_log[s][k];
        }
        __syncthreads();   // protect s_pool/s_log before next chunk
    }
}

// Per-sample CE loss from global logits. One wave per sample, lane = k.
__global__ __launch_bounds__(256) void loss_kernel(
    const float* __restrict__ logits,   // [B, D, K]
    const int*   __restrict__ path,     // [B, D]
    float*       __restrict__ losses)   // [B]
{
    const int wave = threadIdx.x >> 6;
    const int lane = threadIdx.x & 63;
    const int b = blockIdx.x * 4 + wave;
    if (b >= BATCH) return;
    const float* lg = logits + (size_t)b * DEPTH * FANOUT;
    float loss = 0.f;
#pragma unroll
    for (int d = 0; d < DEPTH; ++d) {
        float x = lg[d * FANOUT + lane];
        float m = x;
#pragma unroll
        for (int off = 32; off > 0; off >>= 1)
            m = fmaxf(m, __shfl_xor(m, off, 64));
        float e = expf(x - m);
#pragma unroll
        for (int off = 32; off > 0; off >>= 1)
            e += __shfl_xor(e, off, 64);
        float lse = m + logf(e);
        int t = path[b * DEPTH + d];
        loss += lse - __shfl(x, t, 64);
    }
    if (lane == 0) losses[b] = loss;
}

extern "C" void kernel_launch(void* const* d_in, const int* in_sizes, int n_in,
                              void* d_out, int out_size, void* d_ws, size_t ws_size,
                              hipStream_t stream) {
    const float* pooled = (const float*)d_in[0];  // [B, H]
    const int*   nodes  = (const int*)d_in[1];    // [B, D]
    const int*   path   = (const int*)d_in[2];    // [B, D]
    const float* W      = (const float*)d_in[3];  // [N, K, H]
    const float* bias   = (const float*)d_in[4];  // [N, K]

    float* losses = (float*)d_out;                // [B]
    float* logits = (float*)d_out + BATCH;        // [B, D, K]
    int*   ws     = (int*)d_ws;

    hipMemsetAsync(ws, 0, WS_ZERO_INTS * sizeof(int), stream);
    hipLaunchKernelGGL(bin_kernel, dim3((NPAIRS + 255) / 256), dim3(256),
                       0, stream, nodes, ws);
    hipLaunchKernelGGL(node_gemm_kernel, dim3(NNODES + NTAIL), dim3(256),
                       0, stream, pooled, W, bias, nodes, ws, logits);
    hipLaunchKernelGGL(loss_kernel, dim3((BATCH + 3) / 4), dim3(256),
                       0, stream, logits, path, losses);
}